// Round 3
// baseline (241.157 us; speedup 1.0000x reference)
//
#include <hip/hip_runtime.h>
#include <cmath>

#define B_   128
#define H_   256
#define W_   256
#define WC_  129
#define L_   182
#define NG_  33    // column groups per image in pass2 (4 cols/group * 33 >= 129)
#define PI_F 3.14159265358979f

// ---------------------------------------------------------------------------
// Wave-synchronous 256-point DIF FFT across one 64-lane wave.
// Lane l holds 4 complex elements in registers: slot j = x[l + 64*j].
// Output: storage index q = l + 64*j holds X[bitrev8(q)].
// ---------------------------------------------------------------------------
__device__ __forceinline__ void fft256_wave(float vr[4], float vi[4], int l) {
  float c0, s0;
  __sincosf(-2.f * PI_F * (float)l / 256.f, &s0, &c0);  // w0 = W256^l
  {
    float ur = vr[0] + vr[2], ui = vi[0] + vi[2];
    float dr = vr[0] - vr[2], di = vi[0] - vi[2];
    vr[0] = ur; vi[0] = ui;
    vr[2] = dr * c0 - di * s0; vi[2] = dr * s0 + di * c0;
    float c1 = s0, s1 = -c0;
    ur = vr[1] + vr[3]; ui = vi[1] + vi[3];
    dr = vr[1] - vr[3]; di = vi[1] - vi[3];
    vr[1] = ur; vi[1] = ui;
    vr[3] = dr * c1 - di * s1; vi[3] = dr * s1 + di * c1;
  }
  {
    float c2 = c0 * c0 - s0 * s0, s2 = 2.f * c0 * s0;
    float ur = vr[0] + vr[1], ui = vi[0] + vi[1];
    float dr = vr[0] - vr[1], di = vi[0] - vi[1];
    vr[0] = ur; vi[0] = ui;
    vr[1] = dr * c2 - di * s2; vi[1] = dr * s2 + di * c2;
    ur = vr[2] + vr[3]; ui = vi[2] + vi[3];
    dr = vr[2] - vr[3]; di = vi[2] - vi[3];
    vr[2] = ur; vi[2] = ui;
    vr[3] = dr * c2 - di * s2; vi[3] = dr * s2 + di * c2;
  }
  #pragma unroll
  for (int h = 32; h >= 1; h >>= 1) {
    int i = l & (h - 1);
    float c, s;
    __sincosf(-PI_F * (float)i / (float)h, &s, &c);
    bool up = (l & h) != 0;
    float cc = up ? c : 1.f;
    float ss = up ? s : 0.f;
    float sgn = up ? -1.f : 1.f;
    #pragma unroll
    for (int j = 0; j < 4; ++j) {
      float br = __shfl_xor(vr[j], h, 64);
      float bi = __shfl_xor(vi[j], h, 64);
      float tr = fmaf(sgn, vr[j], br);
      float ti = fmaf(sgn, vi[j], bi);
      vr[j] = tr * cc - ti * ss;
      vi[j] = tr * ss + ti * cc;
    }
  }
}

#define P1_ROWS 16
#define P1_STRIDE 259  // float2 LDS stride breaks pow2 bank pattern

// Pass 1: luma + row FFT. Block = 1024 thr = 16 waves = 16 rows of one image.
// Register FFT, then LDS transpose -> inter[b][k][row] written coalesced.
__global__ __launch_bounds__(1024) void pass1_kernel(
    const float* __restrict__ data, float2* __restrict__ inter) {
  __shared__ float2 tile[P1_ROWS * P1_STRIDE];
  int tid = threadIdx.x;
  int w = tid >> 6, l = tid & 63;
  int b = blockIdx.x >> 4;
  int row0 = (blockIdx.x & 15) * P1_ROWS;
  int row = row0 + w;
  const float* p0 = data + ((size_t)b * 3) * (H_ * W_) + (size_t)row * W_;
  float vr[4], vi[4];
  #pragma unroll
  for (int j = 0; j < 4; ++j) {
    int i = l + 64 * j;
    float r = p0[i], g = p0[H_ * W_ + i], bl = p0[2 * H_ * W_ + i];
    vr[j] = fmaf(0.299f, r, fmaf(0.587f, g, 0.114f * bl));
    vi[j] = 0.f;
  }
  fft256_wave(vr, vi, l);
  #pragma unroll
  for (int j = 0; j < 4; ++j)
    tile[w * P1_STRIDE + l + 64 * j] = make_float2(vr[j], vi[j]);
  __syncthreads();
  // inter[(b*WC+k)*H + row0 + r] = X_row(k); X(k) sits at storage q=bitrev8(k)
  for (int f = tid; f < WC_ * P1_ROWS; f += 1024) {
    int k = f >> 4;
    int r = f & 15;
    int q = (int)(__brev((unsigned)k) >> 24);
    inter[((size_t)b * WC_ + k) * H_ + row0 + r] = tile[r * P1_STRIDE + q];
  }
}

// Pass 2: column FFT + log-power + radial binning into per-block LDS bins,
// flushed with PLAIN stores to partial[b][g][L] (no init, no atomics).
__global__ __launch_bounds__(256) void pass2_kernel(
    const float2* __restrict__ inter, const int* __restrict__ radius,
    float* __restrict__ partial) {
  __shared__ float lbins[L_];
  int tid = threadIdx.x;
  int wv = tid >> 6, l = tid & 63;
  int b = blockIdx.x / NG_;
  int g = blockIdx.x - b * NG_;
  int k = g * 4 + wv;
  for (int i = tid; i < L_; i += 256) lbins[i] = 0.f;
  __syncthreads();
  if (k < WC_) {
    const float2* p = inter + ((size_t)b * WC_ + k) * H_;
    float vr[4], vi[4];
    #pragma unroll
    for (int j = 0; j < 4; ++j) {
      float2 v = p[l + 64 * j];
      vr[j] = v.x; vi[j] = v.y;
    }
    fft256_wave(vr, vi, l);
    int rb = 4 * (int)(__brev((unsigned)l) >> 26);
    #pragma unroll
    for (int j = 0; j < 4; ++j) {
      int rf = rb + ((j == 1) ? 2 : (j == 2) ? 1 : j);  // bitrev2(j)
      float pw = vr[j] * vr[j] + vi[j] * vi[j];
      float val = 20.f * __logf(pw + 1e-8f);
      atomicAdd(&lbins[radius[rf * WC_ + k]], val);
    }
  }
  __syncthreads();
  float* pp = partial + ((size_t)b * NG_ + g) * L_;
  for (int i = tid; i < L_; i += 256) pp[i] = lbins[i];
}

// One block per batch sample: reduce 33 partial-bin groups, recompute counts
// from radius (L2-resident), segment mean, min-max normalize, L1 vs mean.
// Writes per-sample loss with a plain store.
__global__ __launch_bounds__(256) void loss_kernel(
    const float* __restrict__ partial, const int* __restrict__ radius,
    const float* __restrict__ mean, float* __restrict__ lpart) {
  int b = blockIdx.x;
  int t = threadIdx.x;
  __shared__ float cnt[L_];
  __shared__ float prof[L_];
  __shared__ float red[256];
  for (int i = t; i < L_; i += 256) cnt[i] = 0.f;
  __syncthreads();
  for (int i = t; i < H_ * WC_; i += 256) atomicAdd(&cnt[radius[i]], 1.f);
  // sum partial groups meanwhile (no dependency on cnt yet)
  float acc = 0.f;
  if (t < L_) {
    const float* pb = partial + (size_t)b * NG_ * L_;
    #pragma unroll 3
    for (int g = 0; g < NG_; ++g) acc += pb[g * L_ + t];
  }
  __syncthreads();
  if (t < L_) prof[t] = acc / cnt[t];
  __syncthreads();
  red[t] = (t < L_) ? prof[t] : INFINITY;
  __syncthreads();
  for (int s = 128; s > 0; s >>= 1) {
    if (t < s) red[t] = fminf(red[t], red[t + s]);
    __syncthreads();
  }
  float mn = red[0];
  __syncthreads();
  red[t] = (t < L_) ? (prof[t] - mn) : -INFINITY;
  __syncthreads();
  for (int s = 128; s > 0; s >>= 1) {
    if (t < s) red[t] = fmaxf(red[t], red[t + s]);
    __syncthreads();
  }
  float mx = red[0];
  __syncthreads();
  red[t] = (t < L_) ? fabsf((prof[t] - mn) / mx - mean[t]) : 0.f;
  __syncthreads();
  for (int s = 128; s > 0; s >>= 1) {
    if (t < s) red[t] += red[t + s];
    __syncthreads();
  }
  if (t == 0) lpart[b] = red[0];
}

// Final: one wave sums the 128 per-sample losses, plain store to out.
__global__ __launch_bounds__(64) void final_kernel(
    const float* __restrict__ lpart, float* __restrict__ out) {
  int l = threadIdx.x;
  float v = lpart[l] + lpart[l + 64];
  #pragma unroll
  for (int h = 32; h >= 1; h >>= 1) v += __shfl_xor(v, h, 64);
  if (l == 0) out[0] = v;
}

extern "C" void kernel_launch(void* const* d_in, const int* in_sizes, int n_in,
                              void* d_out, int out_size, void* d_ws, size_t ws_size,
                              hipStream_t stream) {
  const float* data   = (const float*)d_in[0];  // [128,3,256,256] f32
  const float* mean   = (const float*)d_in[1];  // [182] f32
  const int*   radius = (const int*)d_in[2];    // [256,129] i32
  float* out = (float*)d_out;                   // scalar f32

  float2* inter = (float2*)d_ws;                          // [B][WC][H] complex
  size_t inter_bytes = (size_t)B_ * WC_ * H_ * sizeof(float2);
  float* partial = (float*)((char*)d_ws + inter_bytes);   // [B][NG][L]
  float* lpart   = partial + (size_t)B_ * NG_ * L_;       // [B]

  pass1_kernel<<<B_ * 16, 1024, 0, stream>>>(data, inter);
  pass2_kernel<<<B_ * NG_, 256, 0, stream>>>(inter, radius, partial);
  loss_kernel<<<B_, 256, 0, stream>>>(partial, radius, mean, lpart);
  final_kernel<<<1, 64, 0, stream>>>(lpart, out);
}

// Round 4
// 194.312 us; speedup vs baseline: 1.2411x; 1.2411x over previous
//
#include <hip/hip_runtime.h>
#include <cmath>

#define B_   128
#define H_   256
#define W_   256
#define WC_  129
#define L_   182
#define NG_  33    // column groups per image in pass2 (4 cols/group * 33 >= 129)
#define PI_F 3.14159265358979f

// ---------------------------------------------------------------------------
// Wave-synchronous 256-point DIF FFT across one 64-lane wave.
// Lane l holds 4 complex elements in registers: slot j = x[l + 64*j].
// Output: storage index q = l + 64*j holds X[bitrev8(q)].
// ---------------------------------------------------------------------------
__device__ __forceinline__ void fft256_wave(float vr[4], float vi[4], int l) {
  float c0, s0;
  __sincosf(-2.f * PI_F * (float)l / 256.f, &s0, &c0);  // w0 = W256^l
  {
    float ur = vr[0] + vr[2], ui = vi[0] + vi[2];
    float dr = vr[0] - vr[2], di = vi[0] - vi[2];
    vr[0] = ur; vi[0] = ui;
    vr[2] = dr * c0 - di * s0; vi[2] = dr * s0 + di * c0;
    float c1 = s0, s1 = -c0;
    ur = vr[1] + vr[3]; ui = vi[1] + vi[3];
    dr = vr[1] - vr[3]; di = vi[1] - vi[3];
    vr[1] = ur; vi[1] = ui;
    vr[3] = dr * c1 - di * s1; vi[3] = dr * s1 + di * c1;
  }
  {
    float c2 = c0 * c0 - s0 * s0, s2 = 2.f * c0 * s0;
    float ur = vr[0] + vr[1], ui = vi[0] + vi[1];
    float dr = vr[0] - vr[1], di = vi[0] - vi[1];
    vr[0] = ur; vi[0] = ui;
    vr[1] = dr * c2 - di * s2; vi[1] = dr * s2 + di * c2;
    ur = vr[2] + vr[3]; ui = vi[2] + vi[3];
    dr = vr[2] - vr[3]; di = vi[2] - vi[3];
    vr[2] = ur; vi[2] = ui;
    vr[3] = dr * c2 - di * s2; vi[3] = dr * s2 + di * c2;
  }
  #pragma unroll
  for (int h = 32; h >= 1; h >>= 1) {
    int i = l & (h - 1);
    float c, s;
    __sincosf(-PI_F * (float)i / (float)h, &s, &c);
    bool up = (l & h) != 0;
    float cc = up ? c : 1.f;
    float ss = up ? s : 0.f;
    float sgn = up ? -1.f : 1.f;
    #pragma unroll
    for (int j = 0; j < 4; ++j) {
      float br = __shfl_xor(vr[j], h, 64);
      float bi = __shfl_xor(vi[j], h, 64);
      float tr = fmaf(sgn, vr[j], br);
      float ti = fmaf(sgn, vi[j], bi);
      vr[j] = tr * cc - ti * ss;
      vi[j] = tr * ss + ti * cc;
    }
  }
}

#define P1_PAIRS 16
#define P1_STRIDE 259  // float2 LDS stride breaks pow2 bank pattern

// Pass 1: luma + row FFT with the two-real-rows-in-one-complex-FFT trick.
// Block = 1024 thr = 16 waves; wave w packs rows (row0+2w, row0+2w+1) as
// re + i*im. After the FFT, the LDS transpose loop unpacks A/B spectra via
// conjugate symmetry and writes inter[b][k][row] as coalesced float4
// (row-pair per thread). 8 blocks per image.
__global__ __launch_bounds__(1024) void pass1_kernel(
    const float* __restrict__ data, float4* __restrict__ inter4) {
  __shared__ float2 tile[P1_PAIRS * P1_STRIDE];
  int tid = threadIdx.x;
  int w = tid >> 6, l = tid & 63;
  int b = blockIdx.x >> 3;
  int row0 = (blockIdx.x & 7) * 32;
  int rowA = row0 + 2 * w;
  const float* pA = data + ((size_t)b * 3) * (H_ * W_) + (size_t)rowA * W_;
  float vr[4], vi[4];
  #pragma unroll
  for (int j = 0; j < 4; ++j) {
    int i = l + 64 * j;
    float r = pA[i], g = pA[H_ * W_ + i], bl = pA[2 * H_ * W_ + i];
    vr[j] = fmaf(0.299f, r, fmaf(0.587f, g, 0.114f * bl));
    r = pA[W_ + i]; g = pA[H_ * W_ + W_ + i]; bl = pA[2 * H_ * W_ + W_ + i];
    vi[j] = fmaf(0.299f, r, fmaf(0.587f, g, 0.114f * bl));
  }
  fft256_wave(vr, vi, l);
  #pragma unroll
  for (int j = 0; j < 4; ++j)
    tile[w * P1_STRIDE + l + 64 * j] = make_float2(vr[j], vi[j]);
  __syncthreads();
  // X(k) sits at storage q = bitrev8(k). Unpack:
  //   A(k) = (Z(k)+conj(Z(N-k)))/2 ; B(k) = (Z(k)-conj(Z(N-k)))/(2i)
  for (int f = tid; f < WC_ * P1_PAIRS; f += 1024) {
    int k = f >> 4;
    int p = f & 15;
    int qk  = (int)(__brev((unsigned)k) >> 24);
    int qnk = (int)(__brev((unsigned)((256 - k) & 255)) >> 24);
    float2 Zk  = tile[p * P1_STRIDE + qk];
    float2 Znk = tile[p * P1_STRIDE + qnk];
    float4 o;
    o.x = 0.5f * (Zk.x + Znk.x);   // A.re
    o.y = 0.5f * (Zk.y - Znk.y);   // A.im
    o.z = 0.5f * (Zk.y + Znk.y);   // B.re
    o.w = 0.5f * (Znk.x - Zk.x);   // B.im
    inter4[((((size_t)b * WC_ + k) * H_ + row0) >> 1) + p] = o;
  }
}

// Pass 2: column FFT + log-power + radial binning into per-block LDS bins,
// flushed with plain stores to partial[b][g][L]. Blocks with b==0 also
// produce the radial count histogram (batch-independent) into cntpart[g][L].
__global__ __launch_bounds__(256) void pass2_kernel(
    const float2* __restrict__ inter, const int* __restrict__ radius,
    float* __restrict__ partial, float* __restrict__ cntpart) {
  __shared__ float lbins[L_];
  __shared__ float lcnt[L_];
  int tid = threadIdx.x;
  int wv = tid >> 6, l = tid & 63;
  int b = blockIdx.x / NG_;
  int g = blockIdx.x - b * NG_;
  int k = g * 4 + wv;
  bool do_cnt = (b == 0);
  for (int i = tid; i < L_; i += 256) lbins[i] = 0.f;
  if (do_cnt)
    for (int i = tid; i < L_; i += 256) lcnt[i] = 0.f;
  __syncthreads();
  if (k < WC_) {
    const float2* p = inter + ((size_t)b * WC_ + k) * H_;
    float vr[4], vi[4];
    #pragma unroll
    for (int j = 0; j < 4; ++j) {
      float2 v = p[l + 64 * j];
      vr[j] = v.x; vi[j] = v.y;
    }
    fft256_wave(vr, vi, l);
    int rb = 4 * (int)(__brev((unsigned)l) >> 26);
    #pragma unroll
    for (int j = 0; j < 4; ++j) {
      int rf = rb + ((j == 1) ? 2 : (j == 2) ? 1 : j);  // bitrev2(j)
      int bin = radius[rf * WC_ + k];
      float pw = vr[j] * vr[j] + vi[j] * vi[j];
      float val = 20.f * __logf(pw + 1e-8f);
      atomicAdd(&lbins[bin], val);
      if (do_cnt) atomicAdd(&lcnt[bin], 1.f);
    }
  }
  __syncthreads();
  float* pp = partial + ((size_t)b * NG_ + g) * L_;
  for (int i = tid; i < L_; i += 256) pp[i] = lbins[i];
  if (do_cnt) {
    float* cp = cntpart + (size_t)g * L_;
    for (int i = tid; i < L_; i += 256) cp[i] = lcnt[i];
  }
}

// One block per batch sample: reduce 33 value+count partials, segment mean,
// min-max normalize, L1 vs mean. Plain store of per-sample loss.
__global__ __launch_bounds__(256) void loss_kernel(
    const float* __restrict__ partial, const float* __restrict__ cntpart,
    const float* __restrict__ mean, float* __restrict__ lpart) {
  int b = blockIdx.x;
  int t = threadIdx.x;
  __shared__ float prof[L_];
  __shared__ float red[256];
  float acc = 0.f, csum = 0.f;
  if (t < L_) {
    const float* pb = partial + (size_t)b * NG_ * L_;
    #pragma unroll 3
    for (int g = 0; g < NG_; ++g) {
      acc  += pb[g * L_ + t];
      csum += cntpart[g * L_ + t];
    }
    prof[t] = acc / csum;
  }
  __syncthreads();
  red[t] = (t < L_) ? prof[t] : INFINITY;
  __syncthreads();
  for (int s = 128; s > 0; s >>= 1) {
    if (t < s) red[t] = fminf(red[t], red[t + s]);
    __syncthreads();
  }
  float mn = red[0];
  __syncthreads();
  red[t] = (t < L_) ? (prof[t] - mn) : -INFINITY;
  __syncthreads();
  for (int s = 128; s > 0; s >>= 1) {
    if (t < s) red[t] = fmaxf(red[t], red[t + s]);
    __syncthreads();
  }
  float mx = red[0];
  __syncthreads();
  red[t] = (t < L_) ? fabsf((prof[t] - mn) / mx - mean[t]) : 0.f;
  __syncthreads();
  for (int s = 128; s > 0; s >>= 1) {
    if (t < s) red[t] += red[t + s];
    __syncthreads();
  }
  if (t == 0) lpart[b] = red[0];
}

// Final: one wave sums the 128 per-sample losses, plain store to out.
__global__ __launch_bounds__(64) void final_kernel(
    const float* __restrict__ lpart, float* __restrict__ out) {
  int l = threadIdx.x;
  float v = lpart[l] + lpart[l + 64];
  #pragma unroll
  for (int h = 32; h >= 1; h >>= 1) v += __shfl_xor(v, h, 64);
  if (l == 0) out[0] = v;
}

extern "C" void kernel_launch(void* const* d_in, const int* in_sizes, int n_in,
                              void* d_out, int out_size, void* d_ws, size_t ws_size,
                              hipStream_t stream) {
  const float* data   = (const float*)d_in[0];  // [128,3,256,256] f32
  const float* mean   = (const float*)d_in[1];  // [182] f32
  const int*   radius = (const int*)d_in[2];    // [256,129] i32
  float* out = (float*)d_out;                   // scalar f32

  float2* inter = (float2*)d_ws;                          // [B][WC][H] complex
  size_t inter_bytes = (size_t)B_ * WC_ * H_ * sizeof(float2);
  float* partial = (float*)((char*)d_ws + inter_bytes);   // [B][NG][L]
  float* cntpart = partial + (size_t)B_ * NG_ * L_;       // [NG][L]
  float* lpart   = cntpart + (size_t)NG_ * L_;            // [B]

  pass1_kernel<<<B_ * 8, 1024, 0, stream>>>(data, (float4*)inter);
  pass2_kernel<<<B_ * NG_, 256, 0, stream>>>(inter, radius, partial, cntpart);
  loss_kernel<<<B_, 256, 0, stream>>>(partial, cntpart, mean, lpart);
  final_kernel<<<1, 64, 0, stream>>>(lpart, out);
}